// Round 1
// baseline (250.795 us; speedup 1.0000x reference)
//
#include <hip/hip_runtime.h>
#include <hip/hip_bf16.h>

// NT-Xent loss, fused. N=4096, D=256, T=0.5.
// d_ws layout: [reps bf16 2N*D | pos f32 N | partial f32 2N*NSPLIT]
// loss_i = log(sum_j exp(sim_ij/T) - e^2) - pos_i/T ; out = mean(loss)

#define D      256
#define KC     8            // K-chunks of 32 (D/32)
#define BM     128          // rows per workgroup (8 waves x 16 rows)
#define NSPLIT 8            // column-dimension splits
#define CEXP   2.885390081777926f  // 1/(T*ln2), T=0.5 -> exp(x/T)=2^(x*CEXP)
#define E2     7.38905609893065f   // exp(1/T) = e^2, the diagonal term

typedef __bf16 bf16x8 __attribute__((ext_vector_type(8)));
typedef float  f32x4  __attribute__((ext_vector_type(4)));

static __device__ __forceinline__ unsigned short f2bf(float x) {
    union { float f; unsigned u; } v; v.f = x;
    unsigned r = v.u + 0x7fffu + ((v.u >> 16) & 1u);   // round-to-nearest-even
    return (unsigned short)(r >> 16);
}

// ---- Kernel A: row L2-normalize both inputs -> bf16 reps; fp32 positives ----
__global__ __launch_bounds__(64) void knorm(const float* __restrict__ zi,
                                            const float* __restrict__ zj,
                                            unsigned short* __restrict__ reps,
                                            float* __restrict__ pos, int n) {
    const int i = blockIdx.x;
    const int lane = threadIdx.x;
    const float4 a = ((const float4*)(zi + (size_t)i * D))[lane];
    const float4 b = ((const float4*)(zj + (size_t)i * D))[lane];
    float si = a.x*a.x + a.y*a.y + a.z*a.z + a.w*a.w;
    float sj = b.x*b.x + b.y*b.y + b.z*b.z + b.w*b.w;
    float sd = a.x*b.x + a.y*b.y + a.z*b.z + a.w*b.w;
    #pragma unroll
    for (int off = 32; off; off >>= 1) {
        si += __shfl_xor(si, off);
        sj += __shfl_xor(sj, off);
        sd += __shfl_xor(sd, off);
    }
    const float inv_i = 1.0f / fmaxf(sqrtf(si), 1e-12f);
    const float inv_j = 1.0f / fmaxf(sqrtf(sj), 1e-12f);
    if (lane == 0) pos[i] = sd * inv_i * inv_j;  // cos(z_i, z_j), fp32 exact path
    ushort4 pa, pb;
    pa.x = f2bf(a.x * inv_i); pa.y = f2bf(a.y * inv_i);
    pa.z = f2bf(a.z * inv_i); pa.w = f2bf(a.w * inv_i);
    pb.x = f2bf(b.x * inv_j); pb.y = f2bf(b.y * inv_j);
    pb.z = f2bf(b.z * inv_j); pb.w = f2bf(b.w * inv_j);
    ((ushort4*)(reps + (size_t)i * D))[lane]       = pa;
    ((ushort4*)(reps + (size_t)(i + n) * D))[lane] = pb;
}

// ---- Kernel B: rowsum_i(split) = sum_{j in split} exp(sim_ij / T) ----
// 8 waves/block, each wave owns 16 rows; A-fragments register-resident;
// iterate column tiles of 16, MFMA 16x16x32 bf16, exp2 epilogue.
__global__ __launch_bounds__(512) void krowsum(const unsigned short* __restrict__ reps,
                                               float* __restrict__ partial, int twoN) {
    const int lane  = threadIdx.x & 63;
    const int w     = threadIdx.x >> 6;
    const int rbase = blockIdx.x * BM + w * 16;
    const int seg   = twoN / NSPLIT;
    const int cb0   = blockIdx.y * seg;
    const int lrow  = lane & 15;
    const int lk    = (lane >> 4) * 8;   // element offset within a 32-wide K chunk

    // A fragment: lane holds A[row=lane&15][k=(lane>>4)*8 + 0..7]
    bf16x8 afrag[KC];
    const unsigned short* arow = reps + (size_t)(rbase + lrow) * D + lk;
    #pragma unroll
    for (int kc = 0; kc < KC; ++kc)
        afrag[kc] = *(const bf16x8*)(arow + kc * 32);

    float rs0 = 0.f, rs1 = 0.f, rs2 = 0.f, rs3 = 0.f;
    const int ntiles = seg / 16;
    for (int ct = 0; ct < ntiles; ++ct) {
        // B fragment for R*R^T: load exactly like A (lane holds R[col][k])
        const unsigned short* brow = reps + (size_t)(cb0 + ct * 16 + lrow) * D + lk;
        f32x4 acc = {0.f, 0.f, 0.f, 0.f};
        #pragma unroll
        for (int kc = 0; kc < KC; ++kc) {
            bf16x8 bfrag = *(const bf16x8*)(brow + kc * 32);
            acc = __builtin_amdgcn_mfma_f32_16x16x32_bf16(afrag[kc], bfrag, acc, 0, 0, 0);
        }
        // C/D layout: col = lane&15, row = (lane>>4)*4 + reg  [m89]
        rs0 += exp2f(acc[0] * CEXP);
        rs1 += exp2f(acc[1] * CEXP);
        rs2 += exp2f(acc[2] * CEXP);
        rs3 += exp2f(acc[3] * CEXP);
    }
    // reduce the 16 column-lanes (low 4 lane bits) per row
    #pragma unroll
    for (int off = 1; off < 16; off <<= 1) {
        rs0 += __shfl_xor(rs0, off);
        rs1 += __shfl_xor(rs1, off);
        rs2 += __shfl_xor(rs2, off);
        rs3 += __shfl_xor(rs3, off);
    }
    if ((lane & 15) == 0) {
        const int rg = rbase + (lane >> 4) * 4;
        float* p = partial + (size_t)rg * NSPLIT + blockIdx.y;
        p[0 * NSPLIT] = rs0;
        p[1 * NSPLIT] = rs1;
        p[2 * NSPLIT] = rs2;
        p[3 * NSPLIT] = rs3;
    }
}

// ---- Kernel C: loss_i = log(rowsum_i - e^2) - 2*pos_i ; out = mean ----
__global__ __launch_bounds__(256) void kfinal(const float* __restrict__ partial,
                                              const float* __restrict__ pos,
                                              float* __restrict__ out,
                                              int twoN, int n) {
    __shared__ float red[256];
    float s = 0.f;
    for (int r = threadIdx.x; r < twoN; r += 256) {
        float dsum = 0.f;
        #pragma unroll
        for (int k = 0; k < NSPLIT; ++k) dsum += partial[(size_t)r * NSPLIT + k];
        dsum -= E2;                       // remove diagonal exp(sim_ii/T)
        const float p = pos[r < n ? r : r - n];
        s += logf(dsum) - 2.0f * p;       // pos/T with T=0.5
    }
    red[threadIdx.x] = s;
    __syncthreads();
    #pragma unroll
    for (int off = 128; off; off >>= 1) {
        if (threadIdx.x < off) red[threadIdx.x] += red[threadIdx.x + off];
        __syncthreads();
    }
    if (threadIdx.x == 0) out[0] = red[0] / (float)twoN;
}

extern "C" void kernel_launch(void* const* d_in, const int* in_sizes, int n_in,
                              void* d_out, int out_size, void* d_ws, size_t ws_size,
                              hipStream_t stream) {
    const float* zi = (const float*)d_in[0];
    const float* zj = (const float*)d_in[1];
    const int n    = in_sizes[0] / D;   // 4096
    const int twoN = 2 * n;             // 8192

    unsigned short* reps = (unsigned short*)d_ws;                       // 2N*D bf16 = 4 MB
    float* pos     = (float*)((char*)d_ws + (size_t)twoN * D * 2);      // N f32
    float* partial = pos + n;                                           // 2N*NSPLIT f32
    float* out     = (float*)d_out;

    knorm<<<n, 64, 0, stream>>>(zi, zj, reps, pos, n);
    dim3 gridB(twoN / BM, NSPLIT);
    krowsum<<<gridB, 512, 0, stream>>>(reps, partial, twoN);
    kfinal<<<1, 256, 0, stream>>>(partial, pos, out, twoN, n);
}

// Round 2
// 242.856 us; speedup vs baseline: 1.0327x; 1.0327x over previous
//
#include <hip/hip_runtime.h>
#include <hip/hip_bf16.h>

// NT-Xent loss, fused. N=4096, D=256, T=0.5.
// d_ws layout: [reps bf16 2N*D | pos f32 N | partial f32 2N*NSPLIT | bsum f32 32]
// loss_i = log(sum_j exp(sim_ij/T) - e^2) - pos_i/T ; out = mean(loss)

#define D      256
#define KC     8            // K-chunks of 32 (D/32)
#define BM     128          // rows per workgroup (8 waves x 16 rows)
#define NSPLIT 8            // column-dimension splits
#define CEXP   2.885390081777926f  // 1/(T*ln2), T=0.5 -> exp(x/T)=2^(x*CEXP)
#define E2     7.38905609893065f   // exp(1/T) = e^2, the diagonal term
#define FBLK   32           // blocks in kfinal1

typedef __bf16 bf16x8 __attribute__((ext_vector_type(8)));
typedef float  f32x4  __attribute__((ext_vector_type(4)));

static __device__ __forceinline__ unsigned short f2bf(float x) {
    union { float f; unsigned u; } v; v.f = x;
    unsigned r = v.u + 0x7fffu + ((v.u >> 16) & 1u);   // round-to-nearest-even
    return (unsigned short)(r >> 16);
}

// ---- Kernel A: row L2-normalize both inputs -> bf16 reps; fp32 positives ----
__global__ __launch_bounds__(64) void knorm(const float* __restrict__ zi,
                                            const float* __restrict__ zj,
                                            unsigned short* __restrict__ reps,
                                            float* __restrict__ pos, int n) {
    const int i = blockIdx.x;
    const int lane = threadIdx.x;
    const float4 a = ((const float4*)(zi + (size_t)i * D))[lane];
    const float4 b = ((const float4*)(zj + (size_t)i * D))[lane];
    float si = a.x*a.x + a.y*a.y + a.z*a.z + a.w*a.w;
    float sj = b.x*b.x + b.y*b.y + b.z*b.z + b.w*b.w;
    float sd = a.x*b.x + a.y*b.y + a.z*b.z + a.w*b.w;
    #pragma unroll
    for (int off = 32; off; off >>= 1) {
        si += __shfl_xor(si, off);
        sj += __shfl_xor(sj, off);
        sd += __shfl_xor(sd, off);
    }
    const float inv_i = 1.0f / fmaxf(sqrtf(si), 1e-12f);
    const float inv_j = 1.0f / fmaxf(sqrtf(sj), 1e-12f);
    if (lane == 0) pos[i] = sd * inv_i * inv_j;  // cos(z_i, z_j), fp32 exact path
    ushort4 pa, pb;
    pa.x = f2bf(a.x * inv_i); pa.y = f2bf(a.y * inv_i);
    pa.z = f2bf(a.z * inv_i); pa.w = f2bf(a.w * inv_i);
    pb.x = f2bf(b.x * inv_j); pb.y = f2bf(b.y * inv_j);
    pb.z = f2bf(b.z * inv_j); pb.w = f2bf(b.w * inv_j);
    ((ushort4*)(reps + (size_t)i * D))[lane]       = pa;
    ((ushort4*)(reps + (size_t)(i + n) * D))[lane] = pb;
}

// ---- Kernel B: rowsum_i(split) = sum_{j in split} exp(sim_ij / T) ----
// 8 waves/block, wave owns 16 rows. 4 independent column tiles in flight
// (4 MFMA chains) + register double-buffer of next K-chunk's B fragments.
__global__ __launch_bounds__(512) void krowsum(const unsigned short* __restrict__ reps,
                                               float* __restrict__ partial, int twoN) {
    const int lane  = threadIdx.x & 63;
    const int w     = threadIdx.x >> 6;
    const int rbase = blockIdx.x * BM + w * 16;
    const int seg   = twoN / NSPLIT;
    const int cb0   = blockIdx.y * seg;
    const int lrow  = lane & 15;
    const int lk    = (lane >> 4) * 8;   // element offset within a 32-wide K chunk

    // A fragment: lane holds A[row=lane&15][k=(lane>>4)*8 + 0..7]
    bf16x8 afrag[KC];
    const unsigned short* arow = reps + (size_t)(rbase + lrow) * D + lk;
    #pragma unroll
    for (int kc = 0; kc < KC; ++kc)
        afrag[kc] = *(const bf16x8*)(arow + kc * 32);

    float rs0 = 0.f, rs1 = 0.f, rs2 = 0.f, rs3 = 0.f;
    const int ngrp = seg / 64;           // groups of 4 col-tiles (64 cols)
    for (int g = 0; g < ngrp; ++g) {
        const unsigned short* b0 = reps + (size_t)(cb0 + g * 64 + lrow) * D + lk;
        f32x4 acc0 = {0.f,0.f,0.f,0.f}, acc1 = {0.f,0.f,0.f,0.f};
        f32x4 acc2 = {0.f,0.f,0.f,0.f}, acc3 = {0.f,0.f,0.f,0.f};
        bf16x8 bc0 = *(const bf16x8*)(b0);
        bf16x8 bc1 = *(const bf16x8*)(b0 + 16 * D);
        bf16x8 bc2 = *(const bf16x8*)(b0 + 32 * D);
        bf16x8 bc3 = *(const bf16x8*)(b0 + 48 * D);
        #pragma unroll
        for (int kc = 0; kc < KC; ++kc) {
            bf16x8 bn0 = bc0, bn1 = bc1, bn2 = bc2, bn3 = bc3;
            if (kc + 1 < KC) {           // compile-time under full unroll
                const unsigned short* bx = b0 + (kc + 1) * 32;
                bn0 = *(const bf16x8*)(bx);
                bn1 = *(const bf16x8*)(bx + 16 * D);
                bn2 = *(const bf16x8*)(bx + 32 * D);
                bn3 = *(const bf16x8*)(bx + 48 * D);
            }
            acc0 = __builtin_amdgcn_mfma_f32_16x16x32_bf16(afrag[kc], bc0, acc0, 0, 0, 0);
            acc1 = __builtin_amdgcn_mfma_f32_16x16x32_bf16(afrag[kc], bc1, acc1, 0, 0, 0);
            acc2 = __builtin_amdgcn_mfma_f32_16x16x32_bf16(afrag[kc], bc2, acc2, 0, 0, 0);
            acc3 = __builtin_amdgcn_mfma_f32_16x16x32_bf16(afrag[kc], bc3, acc3, 0, 0, 0);
            bc0 = bn0; bc1 = bn1; bc2 = bn2; bc3 = bn3;
        }
        // C/D layout: col = lane&15, row = (lane>>4)*4 + reg  [m89]
        rs0 += __builtin_amdgcn_exp2f(acc0[0]*CEXP) + __builtin_amdgcn_exp2f(acc1[0]*CEXP)
             + __builtin_amdgcn_exp2f(acc2[0]*CEXP) + __builtin_amdgcn_exp2f(acc3[0]*CEXP);
        rs1 += __builtin_amdgcn_exp2f(acc0[1]*CEXP) + __builtin_amdgcn_exp2f(acc1[1]*CEXP)
             + __builtin_amdgcn_exp2f(acc2[1]*CEXP) + __builtin_amdgcn_exp2f(acc3[1]*CEXP);
        rs2 += __builtin_amdgcn_exp2f(acc0[2]*CEXP) + __builtin_amdgcn_exp2f(acc1[2]*CEXP)
             + __builtin_amdgcn_exp2f(acc2[2]*CEXP) + __builtin_amdgcn_exp2f(acc3[2]*CEXP);
        rs3 += __builtin_amdgcn_exp2f(acc0[3]*CEXP) + __builtin_amdgcn_exp2f(acc1[3]*CEXP)
             + __builtin_amdgcn_exp2f(acc2[3]*CEXP) + __builtin_amdgcn_exp2f(acc3[3]*CEXP);
    }
    // reduce the 16 column-lanes (low 4 lane bits) per row
    #pragma unroll
    for (int off = 1; off < 16; off <<= 1) {
        rs0 += __shfl_xor(rs0, off);
        rs1 += __shfl_xor(rs1, off);
        rs2 += __shfl_xor(rs2, off);
        rs3 += __shfl_xor(rs3, off);
    }
    if ((lane & 15) == 0) {
        const int rg = rbase + (lane >> 4) * 4;
        float* p = partial + (size_t)rg * NSPLIT + blockIdx.y;
        p[0 * NSPLIT] = rs0;
        p[1 * NSPLIT] = rs1;
        p[2 * NSPLIT] = rs2;
        p[3 * NSPLIT] = rs3;
    }
}

// ---- Kernel C1: per-row loss, block-level partial sums (32 blocks) ----
__global__ __launch_bounds__(256) void kfinal1(const float* __restrict__ partial,
                                               const float* __restrict__ pos,
                                               float* __restrict__ bsum,
                                               int twoN, int n) {
    __shared__ float red[256];
    const int r = blockIdx.x * 256 + threadIdx.x;   // one row per thread
    float s = 0.f;
    if (r < twoN) {
        const f32x4* pr = (const f32x4*)(partial + (size_t)r * NSPLIT);
        f32x4 v = pr[0];
        #pragma unroll
        for (int q = 1; q < NSPLIT / 4; ++q) {
            f32x4 u = pr[q];
            v[0] += u[0]; v[1] += u[1]; v[2] += u[2]; v[3] += u[3];
        }
        float dsum = (v[0] + v[1]) + (v[2] + v[3]) - E2;
        const float p = pos[r < n ? r : r - n];
        s = logf(dsum) - 2.0f * p;       // pos/T with T=0.5
    }
    red[threadIdx.x] = s;
    __syncthreads();
    #pragma unroll
    for (int off = 128; off; off >>= 1) {
        if (threadIdx.x < off) red[threadIdx.x] += red[threadIdx.x + off];
        __syncthreads();
    }
    if (threadIdx.x == 0) bsum[blockIdx.x] = red[0];
}

// ---- Kernel C2: final mean ----
__global__ __launch_bounds__(64) void kfinal2(const float* __restrict__ bsum,
                                              float* __restrict__ out, int twoN) {
    float s = threadIdx.x < FBLK ? bsum[threadIdx.x] : 0.f;
    #pragma unroll
    for (int off = 32; off; off >>= 1) s += __shfl_xor(s, off);
    if (threadIdx.x == 0) out[0] = s / (float)twoN;
}

extern "C" void kernel_launch(void* const* d_in, const int* in_sizes, int n_in,
                              void* d_out, int out_size, void* d_ws, size_t ws_size,
                              hipStream_t stream) {
    const float* zi = (const float*)d_in[0];
    const float* zj = (const float*)d_in[1];
    const int n    = in_sizes[0] / D;   // 4096
    const int twoN = 2 * n;             // 8192

    unsigned short* reps = (unsigned short*)d_ws;                       // 2N*D bf16 = 4 MB
    float* pos     = (float*)((char*)d_ws + (size_t)twoN * D * 2);      // N f32
    float* partial = pos + n;                                           // 2N*NSPLIT f32
    float* bsum    = partial + (size_t)twoN * NSPLIT;                   // FBLK f32
    float* out     = (float*)d_out;

    knorm<<<n, 64, 0, stream>>>(zi, zj, reps, pos, n);
    dim3 gridB(twoN / BM, NSPLIT);
    krowsum<<<gridB, 512, 0, stream>>>(reps, partial, twoN);
    kfinal1<<<FBLK, 256, 0, stream>>>(partial, pos, bsum, twoN, n);
    kfinal2<<<1, 64, 0, stream>>>(bsum, out, twoN);
}

// Round 3
// 48.878 us; speedup vs baseline: 5.1311x; 4.9687x over previous
//
#include <hip/hip_runtime.h>
#include <hip/hip_bf16.h>

// NT-Xent loss, fused. N=4096, D=256, T=0.5.
// d_ws layout: [reps bf16 2N*D | pos f32 N | partial f32 2N*NSPLIT | bsum f32 32]
// loss_i = log(sum_j exp(sim_ij/T) - e^2) - pos_i/T ; out = mean(loss)

#define D      256
#define KC     8            // K-chunks of 32 elems (D/32)
#define BM     128          // rows per block = 4 waves x 32 rows
#define BN     64           // B-columns staged in LDS per chunk
#define NSPLIT 8            // column-dimension splits
#define CEXP   2.885390081777926f  // 1/(T*ln2): exp(x/T) = 2^(x*CEXP)
#define E2     7.38905609893065f   // exp(1/T) = e^2, diagonal term
#define FBLK   32

typedef __bf16 bf16x8 __attribute__((ext_vector_type(8)));
typedef float  f32x4  __attribute__((ext_vector_type(4)));
typedef __attribute__((address_space(1))) const unsigned int* gas_t;
typedef __attribute__((address_space(3))) unsigned int*       las_t;

static __device__ __forceinline__ void gload_lds16(const void* g, void* l) {
    // 16B/lane direct global->LDS; dest is wave-uniform base + lane*16 (linear)
    __builtin_amdgcn_global_load_lds((gas_t)(uintptr_t)g, (las_t)(uintptr_t)l, 16, 0, 0);
}

static __device__ __forceinline__ unsigned short f2bf(float x) {
    union { float f; unsigned u; } v; v.f = x;
    unsigned r = v.u + 0x7fffu + ((v.u >> 16) & 1u);   // RNE
    return (unsigned short)(r >> 16);
}

// ---- Kernel A: row L2-normalize both inputs -> bf16 reps; fp32 positives ----
__global__ __launch_bounds__(64) void knorm(const float* __restrict__ zi,
                                            const float* __restrict__ zj,
                                            unsigned short* __restrict__ reps,
                                            float* __restrict__ pos, int n) {
    const int i = blockIdx.x;
    const int lane = threadIdx.x;
    const float4 a = ((const float4*)(zi + (size_t)i * D))[lane];
    const float4 b = ((const float4*)(zj + (size_t)i * D))[lane];
    float si = a.x*a.x + a.y*a.y + a.z*a.z + a.w*a.w;
    float sj = b.x*b.x + b.y*b.y + b.z*b.z + b.w*b.w;
    float sd = a.x*b.x + a.y*b.y + a.z*b.z + a.w*b.w;
    #pragma unroll
    for (int off = 32; off; off >>= 1) {
        si += __shfl_xor(si, off);
        sj += __shfl_xor(sj, off);
        sd += __shfl_xor(sd, off);
    }
    const float inv_i = 1.0f / fmaxf(sqrtf(si), 1e-12f);
    const float inv_j = 1.0f / fmaxf(sqrtf(sj), 1e-12f);
    if (lane == 0) pos[i] = sd * inv_i * inv_j;
    ushort4 pa, pb;
    pa.x = f2bf(a.x * inv_i); pa.y = f2bf(a.y * inv_i);
    pa.z = f2bf(a.z * inv_i); pa.w = f2bf(a.w * inv_i);
    pb.x = f2bf(b.x * inv_j); pb.y = f2bf(b.y * inv_j);
    pb.z = f2bf(b.z * inv_j); pb.w = f2bf(b.w * inv_j);
    ((ushort4*)(reps + (size_t)i * D))[lane]       = pa;
    ((ushort4*)(reps + (size_t)(i + n) * D))[lane] = pb;
}

// ---- Kernel B: rowsum_i(split) = sum_{j in split} exp(sim_ij/T) ----
// 4 waves/block, wave owns 32 rows (2 row-tiles). B staged in LDS via
// global_load_lds (dbuf, 2x32KB), XOR-swizzled (pre-swizzled source + swizzled
// ds_read per rule 21). Each B fragment feeds 2 MFMAs.
__global__ __launch_bounds__(256, 2) void krowsum(const unsigned short* __restrict__ reps,
                                                  float* __restrict__ partial, int twoN) {
    __shared__ unsigned short buf[2][BN * D];   // 2 x 32 KB
    const int lane  = threadIdx.x & 63;
    const int rbase = blockIdx.x * BM + (threadIdx.x >> 6) * 32;
    const int seg   = twoN / NSPLIT;
    const int cb0   = blockIdx.y * seg;
    const int lrow  = lane & 15;
    const int lkb   = (lane >> 4) * 16;  // byte offset of this lane's 16B in a 64B k-chunk
    const int swz   = (lrow & 7) << 4;   // row-XOR swizzle for compute-side reads
    const int NCH   = seg / BN;

    // A fragments, register-resident: 2 row-tiles x 8 k-chunks (64 VGPRs)
    bf16x8 afrag[2][KC];
    #pragma unroll
    for (int rt = 0; rt < 2; ++rt) {
        const char* ar = (const char*)(reps + (size_t)(rbase + rt * 16 + lrow) * D) + lkb;
        #pragma unroll
        for (int kc = 0; kc < KC; ++kc)
            afrag[rt][kc] = *(const bf16x8*)(ar + kc * 64);
    }

    float rs[2][4];
    #pragma unroll
    for (int rt = 0; rt < 2; ++rt)
        #pragma unroll
        for (int e = 0; e < 4; ++e) rs[rt][e] = 0.f;

    // ---- stage chunk c into buf[b]: contiguous 32KB, source pre-swizzled ----
    #define STAGE(b, c)                                                           \
        do {                                                                      \
            const char* src_ = (const char*)(reps + (size_t)(cb0 + (c) * BN) * D);\
            _Pragma("unroll")                                                     \
            for (int i_ = 0; i_ < 8; ++i_) {                                      \
                int o_   = i_ * 4096 + threadIdx.x * 16;                          \
                int row_ = o_ >> 9;                                               \
                int cb_  = o_ & 511;                                              \
                gload_lds16(src_ + row_ * 512 + (cb_ ^ ((row_ & 7) << 4)),        \
                            (char*)(&buf[(b)][0]) + o_);                          \
            }                                                                     \
        } while (0)

    STAGE(0, 0);
    __syncthreads();   // emits s_waitcnt vmcnt(0) before s_barrier
    int cur = 0;
    for (int c = 0; c < NCH; ++c) {
        if (c + 1 < NCH) STAGE(cur ^ 1, c + 1);   // issue next-chunk loads first
        const char* bb = (const char*)(&buf[cur][0]);
        f32x4 acc[2][4];
        #pragma unroll
        for (int rt = 0; rt < 2; ++rt)
            #pragma unroll
            for (int t = 0; t < 4; ++t) acc[rt][t] = (f32x4){0.f, 0.f, 0.f, 0.f};
        #pragma unroll
        for (int kc = 0; kc < KC; ++kc) {
            bf16x8 bf[4];
            #pragma unroll
            for (int t = 0; t < 4; ++t)
                bf[t] = *(const bf16x8*)(bb + (t * 16 + lrow) * 512 + ((kc * 64 + lkb) ^ swz));
            #pragma unroll
            for (int rt = 0; rt < 2; ++rt)
                #pragma unroll
                for (int t = 0; t < 4; ++t)
                    acc[rt][t] = __builtin_amdgcn_mfma_f32_16x16x32_bf16(
                        afrag[rt][kc], bf[t], acc[rt][t], 0, 0, 0);
        }
        // C/D layout: col = lane&15, row = (lane>>4)*4 + e  [m89]
        #pragma unroll
        for (int rt = 0; rt < 2; ++rt)
            #pragma unroll
            for (int e = 0; e < 4; ++e)
                rs[rt][e] += __builtin_amdgcn_exp2f(acc[rt][0][e] * CEXP)
                           + __builtin_amdgcn_exp2f(acc[rt][1][e] * CEXP)
                           + __builtin_amdgcn_exp2f(acc[rt][2][e] * CEXP)
                           + __builtin_amdgcn_exp2f(acc[rt][3][e] * CEXP);
        __syncthreads();   // drains vmcnt (staging) + lgkmcnt (ds_reads)
        cur ^= 1;
    }

    // reduce the 16 column-lanes (low 4 lane bits) per row
    #pragma unroll
    for (int rt = 0; rt < 2; ++rt)
        #pragma unroll
        for (int e = 0; e < 4; ++e)
            #pragma unroll
            for (int off = 1; off < 16; off <<= 1)
                rs[rt][e] += __shfl_xor(rs[rt][e], off);
    if ((lane & 15) == 0) {
        #pragma unroll
        for (int rt = 0; rt < 2; ++rt) {
            const int rg = rbase + rt * 16 + (lane >> 4) * 4;
            #pragma unroll
            for (int e = 0; e < 4; ++e)
                partial[(size_t)(rg + e) * NSPLIT + blockIdx.y] = rs[rt][e];
        }
    }
}

// ---- Kernel C1: per-row loss, block partial sums ----
__global__ __launch_bounds__(256) void kfinal1(const float* __restrict__ partial,
                                               const float* __restrict__ pos,
                                               float* __restrict__ bsum,
                                               int twoN, int n) {
    __shared__ float red[256];
    const int r = blockIdx.x * 256 + threadIdx.x;
    float s = 0.f;
    if (r < twoN) {
        const f32x4* pr = (const f32x4*)(partial + (size_t)r * NSPLIT);
        f32x4 v = pr[0];
        #pragma unroll
        for (int q = 1; q < NSPLIT / 4; ++q) {
            f32x4 u = pr[q];
            v[0] += u[0]; v[1] += u[1]; v[2] += u[2]; v[3] += u[3];
        }
        float dsum = (v[0] + v[1]) + (v[2] + v[3]) - E2;
        const float p = pos[r < n ? r : r - n];
        s = logf(dsum) - 2.0f * p;        // pos/T with T=0.5
    }
    red[threadIdx.x] = s;
    __syncthreads();
    #pragma unroll
    for (int off = 128; off; off >>= 1) {
        if (threadIdx.x < off) red[threadIdx.x] += red[threadIdx.x + off];
        __syncthreads();
    }
    if (threadIdx.x == 0) bsum[blockIdx.x] = red[0];
}

// ---- Kernel C2: final mean ----
__global__ __launch_bounds__(64) void kfinal2(const float* __restrict__ bsum,
                                              float* __restrict__ out, int twoN) {
    float s = threadIdx.x < FBLK ? bsum[threadIdx.x] : 0.f;
    #pragma unroll
    for (int off = 32; off; off >>= 1) s += __shfl_xor(s, off);
    if (threadIdx.x == 0) out[0] = s / (float)twoN;
}

extern "C" void kernel_launch(void* const* d_in, const int* in_sizes, int n_in,
                              void* d_out, int out_size, void* d_ws, size_t ws_size,
                              hipStream_t stream) {
    const float* zi = (const float*)d_in[0];
    const float* zj = (const float*)d_in[1];
    const int n    = in_sizes[0] / D;   // 4096
    const int twoN = 2 * n;             // 8192

    unsigned short* reps = (unsigned short*)d_ws;                   // 2N*D bf16 = 4 MB
    float* pos     = (float*)((char*)d_ws + (size_t)twoN * D * 2);  // N f32
    float* partial = pos + n;                                       // 2N*NSPLIT f32
    float* bsum    = partial + (size_t)twoN * NSPLIT;               // FBLK f32
    float* out     = (float*)d_out;

    knorm<<<n, 64, 0, stream>>>(zi, zj, reps, pos, n);
    dim3 gridB(twoN / BM, NSPLIT);
    krowsum<<<gridB, 256, 0, stream>>>(reps, partial, twoN);
    kfinal1<<<FBLK, 256, 0, stream>>>(partial, pos, bsum, twoN, n);
    kfinal2<<<1, 64, 0, stream>>>(bsum, out, twoN);
}